// Round 13
// baseline (127.702 us; speedup 1.0000x reference)
//
#include <hip/hip_runtime.h>
#include <hip/hip_bf16.h>
#include <math.h>

// GAT, 3 layers, N=4096, H=8, O=64, F_in=256 then 512.
// Sparse softmax over ~1%-dense adj (+self loops) is EXACT vs masked dense.
//
// R2-R8: MFMA GEMMs; fused prep/sd/convA; fp16 Wh gather everywhere.
// R9/R10: gemm1 plain fp16; prep grid fixed.
// R11/R12: 16-granularity gather + 1-deep software prefetch (115.9us).
// R13(this): gather issues a FULL 64-slot window of loads back-to-back
//     (8 independent 1KB wave-loads in flight vs 2) with uniform 16-slot
//     guards (same padded-load count as R12; cnt is block-uniform and
//     lst/w LDS are fully padded so extra slots are w=0 self-loops).
//     Rows with cnt>64 (expected ~0.6/4096) take a second window pass.

#define NODES 4096
#define HEADS 8
#define HID   64
#define FOUT  512   // HEADS*HID
#define MAXNBR 128

typedef _Float16 half8 __attribute__((ext_vector_type(8)));
typedef _Float16 half4 __attribute__((ext_vector_type(4)));
typedef float f32x4 __attribute__((ext_vector_type(4)));

// ---------------------------------------------------------------------------
// device helpers for the fused prep kernel
// ---------------------------------------------------------------------------
__device__ inline void conv_a_elem(const float* __restrict__ in,
                                   _Float16* __restrict__ out, int K, int id) {
  // plain fp16 A [4096][K]; id in [0, NODES*K/4)
  int perRow = K >> 2;
  int m = id / perRow, c = (id - m * perRow) * 4;
  float4 v = *(const float4*)(in + (size_t)m * K + c);
  half4 hi;
  hi[0] = (_Float16)v.x; hi[1] = (_Float16)v.y;
  hi[2] = (_Float16)v.z; hi[3] = (_Float16)v.w;
  *(half4*)(out + (size_t)m * K + c) = hi;
}

__device__ inline void conv_w_elem(const float* __restrict__ W,
                                   _Float16* __restrict__ Bc, int K, int id) {
  // plain fp16 B [512][K] (n-major); id in [0, HEADS*64*K/8)
  int n = id & 63;
  int r = id >> 6;
  int kchunks = K >> 3;
  int kc = r % kchunks, h = r / kchunks;
  int k0 = kc * 8;
  half8 hi;
#pragma unroll
  for (int i = 0; i < 8; ++i)
    hi[i] = (_Float16)W[((size_t)h * K + k0 + i) * 64 + n];
  *(half8*)(Bc + (size_t)(h * 64 + n) * K + k0) = hi;
}

// ---------------------------------------------------------------------------
// Fused prep: block-range partitioned. Element counts per range:
//   build_nbr: 4096 rows / 4 waves-per-block          -> 1024 blocks [0,1024)
//   convA:     4096*256/4 = 262144 f4-elems / 256 thr -> 1024 blocks [1024,2048)
//   convW1:    8*64*(256/8) = 16384 / 256             ->   64 blocks [2048,2112)
//   convW2:    8*64*(512/8) = 32768 / 256             ->  128 blocks [2112,2240)
//   convW3:    same                                    ->  128 blocks [2240,2368)
// ---------------------------------------------------------------------------
__global__ __launch_bounds__(256) void prep_kernel(
    const float* __restrict__ adj, int* __restrict__ nbr_cnt,
    int* __restrict__ nbr, const float* __restrict__ features,
    _Float16* __restrict__ Ac1,
    const float* __restrict__ W1, const float* __restrict__ W2,
    const float* __restrict__ W3, _Float16* __restrict__ Bc1,
    _Float16* __restrict__ Bc2, _Float16* __restrict__ Bc3) {
  const int b = blockIdx.x;
  if (b < 1024) {
    int wave = b * 4 + (threadIdx.x >> 6);
    int lane = threadIdx.x & 63;
    const float4* arow = (const float4*)(adj + (size_t)wave * NODES);
    int* lst = nbr + (size_t)wave * MAXNBR;
    int base = 0;
    float4 a0 = arow[lane];
    float4 a1 = arow[64 + lane];
#pragma unroll 4
    for (int it = 0; it < 16; ++it) {
      float4 cur = a0;
      a0 = a1;
      if (it + 2 < 16) a1 = arow[(it + 2) * 64 + lane];
      const int colbase = it * 256 + lane * 4;
#pragma unroll
      for (int c = 0; c < 4; ++c) {
        float v = (c == 0) ? cur.x : (c == 1) ? cur.y : (c == 2) ? cur.z : cur.w;
        unsigned long long mask = __ballot(v > 0.0f);
        if (v > 0.0f) {
          int pos = base + __popcll(mask & ((1ull << lane) - 1ull));
          if (pos < MAXNBR) lst[pos] = colbase + c;
        }
        base += __popcll(mask);
      }
    }
    if (lane == 0) nbr_cnt[wave] = base < MAXNBR ? base : MAXNBR;
  } else if (b < 2048) {
    conv_a_elem(features, Ac1, 256, (b - 1024) * 256 + threadIdx.x);
  } else if (b < 2112) {
    conv_w_elem(W1, Bc1, 256, (b - 2048) * 256 + threadIdx.x);
  } else if (b < 2240) {
    conv_w_elem(W2, Bc2, 512, (b - 2112) * 256 + threadIdx.x);
  } else {
    conv_w_elem(W3, Bc3, 512, (b - 2240) * 256 + threadIdx.x);
  }
}

// ---------------------------------------------------------------------------
// C16[4096,512] = A[4096,Keff] * B[512,Keff]^T (fp16 in, fp32 accum, fp16 out)
// 64x64 tile, BK=32, 4 waves, 2x2 frags of 16x16x32 MFMA.
// Fused epilogue: s[h,m], d[h,m] computed fp32-exact from accumulators.
// ---------------------------------------------------------------------------
__global__ __launch_bounds__(256) void gemm_mfma(
    const _Float16* __restrict__ A,   // [4096][Keff]
    const _Float16* __restrict__ B,   // [512][Keff]  (n-major)
    _Float16* __restrict__ C16,       // [4096][512]
    const float* __restrict__ a_src,  // [8][64]
    const float* __restrict__ a_dst,  // [8][64]
    float* __restrict__ sbuf,         // [8][4096]
    float* __restrict__ dbuf,         // [8][4096]
    int Keff) {
  __shared__ _Float16 As[64 * 40];
  __shared__ _Float16 Bs[64 * 40];
  __shared__ float sS[2][64];
  __shared__ float sD[2][64];

  const int t    = threadIdx.x;
  const int m0   = blockIdx.y * 64;
  const int n0   = blockIdx.x * 64;
  const int h    = blockIdx.x;
  const int w    = t >> 6;
  const int lane = t & 63;
  const int wr   = (w >> 1) * 32;
  const int wc   = (w & 1) * 32;
  const int lr   = lane & 15;
  const int lk   = (lane >> 4) * 8;

  const int sr = t >> 2;
  const int sc = (t & 3) * 8;
  const _Float16* gA = A + (size_t)(m0 + sr) * Keff + sc;
  const _Float16* gB = B + (size_t)(n0 + sr) * Keff + sc;

  f32x4 acc00 = {}, acc01 = {}, acc10 = {}, acc11 = {};

  half8 av = *(const half8*)(gA);
  half8 bv = *(const half8*)(gB);

  for (int k0 = 0; k0 < Keff; k0 += 32) {
    __syncthreads();
    *(half8*)(&As[sr * 40 + sc]) = av;
    *(half8*)(&Bs[sr * 40 + sc]) = bv;
    __syncthreads();
    if (k0 + 32 < Keff) {
      av = *(const half8*)(gA + k0 + 32);
      bv = *(const half8*)(gB + k0 + 32);
    }
    half8 a0 = *(const half8*)(&As[(wr + lr) * 40 + lk]);
    half8 a1 = *(const half8*)(&As[(wr + 16 + lr) * 40 + lk]);
    half8 b0 = *(const half8*)(&Bs[(wc + lr) * 40 + lk]);
    half8 b1 = *(const half8*)(&Bs[(wc + 16 + lr) * 40 + lk]);
    acc00 = __builtin_amdgcn_mfma_f32_16x16x32_f16(a0, b0, acc00, 0, 0, 0);
    acc01 = __builtin_amdgcn_mfma_f32_16x16x32_f16(a0, b1, acc01, 0, 0, 0);
    acc10 = __builtin_amdgcn_mfma_f32_16x16x32_f16(a1, b0, acc10, 0, 0, 0);
    acc11 = __builtin_amdgcn_mfma_f32_16x16x32_f16(a1, b1, acc11, 0, 0, 0);
  }

  // C/D layout: col = lane&15, row = (lane>>4)*4 + reg  [m89/m91 verified]
  const int cm = (lane >> 4) * 4;
#pragma unroll
  for (int j = 0; j < 4; ++j) {
    int m  = m0 + wr + cm + j;
    int m2 = m + 16;
    C16[(size_t)m * FOUT + n0 + wc + lr]       = (_Float16)acc00[j];
    C16[(size_t)m * FOUT + n0 + wc + 16 + lr]  = (_Float16)acc01[j];
    C16[(size_t)m2 * FOUT + n0 + wc + lr]      = (_Float16)acc10[j];
    C16[(size_t)m2 * FOUT + n0 + wc + 16 + lr] = (_Float16)acc11[j];
  }

  // fused s/d epilogue (fp32-exact from accumulators)
  const float as0 = a_src[(h << 6) + wc + lr];
  const float as1 = a_src[(h << 6) + wc + 16 + lr];
  const float ad0 = a_dst[(h << 6) + wc + lr];
  const float ad1 = a_dst[(h << 6) + wc + 16 + lr];
  float ps[8], pd[8];
#pragma unroll
  for (int j = 0; j < 4; ++j) {
    ps[j]     = acc00[j] * as0 + acc01[j] * as1;
    ps[4 + j] = acc10[j] * as0 + acc11[j] * as1;
    pd[j]     = acc00[j] * ad0 + acc01[j] * ad1;
    pd[4 + j] = acc10[j] * ad0 + acc11[j] * ad1;
  }
#pragma unroll
  for (int off = 1; off < 16; off <<= 1) {
#pragma unroll
    for (int j = 0; j < 8; ++j) {
      ps[j] += __shfl_xor(ps[j], off);
      pd[j] += __shfl_xor(pd[j], off);
    }
  }
  if (lr == 0) {
#pragma unroll
    for (int j = 0; j < 4; ++j) {
      sS[w & 1][wr + cm + j]      = ps[j];
      sS[w & 1][wr + 16 + cm + j] = ps[4 + j];
      sD[w & 1][wr + cm + j]      = pd[j];
      sD[w & 1][wr + 16 + cm + j] = pd[4 + j];
    }
  }
  __syncthreads();
  if (t < 64) {
    sbuf[(size_t)h * NODES + m0 + t] = sS[0][t] + sS[1][t];
    dbuf[(size_t)h * NODES + m0 + t] = sD[0][t] + sD[1][t];
  }
}

// ---------------------------------------------------------------------------
// Sparse masked softmax + PV + ELU. fp16 Wh16 gather: one 64-slot window of
// up to 8 wave-loads issued back-to-back (uniform 16-slot guards), then FMAs.
// cnt is block-uniform; lst/w LDS fully padded (self, w=0) -> guards exact.
// WRITE_AC=1: write next layer's A as fp16 [4096][512]. =0: fp32 out.
// ---------------------------------------------------------------------------
template <int WRITE_AC>
__global__ __launch_bounds__(512) void attn_kernel(
    const int* __restrict__ nbr_cnt, const int* __restrict__ nbr,
    const float* __restrict__ s, const float* __restrict__ d,
    const _Float16* __restrict__ Wh16,
    float* __restrict__ out, _Float16* __restrict__ Ac) {
  __shared__ int   lst_lds[MAXNBR];
  __shared__ float w_lds[HEADS][MAXNBR];

  const int i    = blockIdx.x;
  const int tid  = threadIdx.x;
  const int h    = tid >> 6;
  const int lane = tid & 63;
  const int cnt  = nbr_cnt[i];

  if (tid < MAXNBR)
    lst_lds[tid] = (tid < cnt) ? nbr[(size_t)i * MAXNBR + tid] : i;
  __syncthreads();

  const float s_i = s[(size_t)h * NODES + i];
  const float* dh = d + (size_t)h * NODES;
  float e0 = -1e30f, e1 = -1e30f;
  if (lane < cnt) {
    float e = s_i + dh[lst_lds[lane]];
    e0 = (e >= 0.0f) ? e : 0.2f * e;
  }
  if (lane + 64 < cnt) {
    float e = s_i + dh[lst_lds[lane + 64]];
    e1 = (e >= 0.0f) ? e : 0.2f * e;
  }
  float m = fmaxf(e0, e1);
#pragma unroll
  for (int off = 32; off; off >>= 1) m = fmaxf(m, __shfl_xor(m, off));
  float w0 = (lane < cnt) ? __expf(e0 - m) : 0.0f;
  float w1 = (lane + 64 < cnt) ? __expf(e1 - m) : 0.0f;
  w_lds[h][lane]      = w0;
  w_lds[h][lane + 64] = w1;
  float den = w0 + w1;
#pragma unroll
  for (int off = 32; off; off >>= 1) den += __shfl_xor(den, off);
  const float rden = 1.0f / den;
  __syncthreads();

  // gather: 8 subgroups of 8 lanes; lane covers 8 dims via half8.
  const int g  = lane >> 3;
  const int d8 = (lane & 7) * 8;
  const int cnt16 = (cnt + 15) & ~15;
  const _Float16* base = Wh16 + h * HID + d8;
  float aA[8] = {}, aB[8] = {};

  for (int t0 = 0; t0 < cnt16; t0 += 64) {     // one pass for cnt<=64 (~all)
    const int rem = cnt16 - t0;                // multiple of 16, >= 16
    half8 vA0, vB0, vA1, vB1, vA2, vB2, vA3, vB3;
    float wA0, wB0, wA1, wB1, wA2, wB2, wA3, wB3;
    // ---- issue all loads back-to-back (uniform guards) ----
    {
      const int ta = t0 + g, tb = ta + 8;
      wA0 = w_lds[h][ta]; wB0 = w_lds[h][tb];
      vA0 = *(const half8*)(base + (size_t)lst_lds[ta] * FOUT);
      vB0 = *(const half8*)(base + (size_t)lst_lds[tb] * FOUT);
    }
    if (rem > 16) {
      const int ta = t0 + 16 + g, tb = ta + 8;
      wA1 = w_lds[h][ta]; wB1 = w_lds[h][tb];
      vA1 = *(const half8*)(base + (size_t)lst_lds[ta] * FOUT);
      vB1 = *(const half8*)(base + (size_t)lst_lds[tb] * FOUT);
    }
    if (rem > 32) {
      const int ta = t0 + 32 + g, tb = ta + 8;
      wA2 = w_lds[h][ta]; wB2 = w_lds[h][tb];
      vA2 = *(const half8*)(base + (size_t)lst_lds[ta] * FOUT);
      vB2 = *(const half8*)(base + (size_t)lst_lds[tb] * FOUT);
    }
    if (rem > 48) {
      const int ta = t0 + 48 + g, tb = ta + 8;
      wA3 = w_lds[h][ta]; wB3 = w_lds[h][tb];
      vA3 = *(const half8*)(base + (size_t)lst_lds[ta] * FOUT);
      vB3 = *(const half8*)(base + (size_t)lst_lds[tb] * FOUT);
    }
    // ---- accumulate ----
#pragma unroll
    for (int q = 0; q < 8; ++q) {
      aA[q] += wA0 * (float)vA0[q];
      aB[q] += wB0 * (float)vB0[q];
    }
    if (rem > 16) {
#pragma unroll
      for (int q = 0; q < 8; ++q) {
        aA[q] += wA1 * (float)vA1[q];
        aB[q] += wB1 * (float)vB1[q];
      }
    }
    if (rem > 32) {
#pragma unroll
      for (int q = 0; q < 8; ++q) {
        aA[q] += wA2 * (float)vA2[q];
        aB[q] += wB2 * (float)vB2[q];
      }
    }
    if (rem > 48) {
#pragma unroll
      for (int q = 0; q < 8; ++q) {
        aA[q] += wA3 * (float)vA3[q];
        aB[q] += wB3 * (float)vB3[q];
      }
    }
  }

  float acc[8];
#pragma unroll
  for (int q = 0; q < 8; ++q) acc[q] = aA[q] + aB[q];
#pragma unroll
  for (int off = 8; off <= 32; off <<= 1)
#pragma unroll
    for (int q = 0; q < 8; ++q) acc[q] += __shfl_xor(acc[q], off);

  if (lane < 8) {
    float o[8];
#pragma unroll
    for (int q = 0; q < 8; ++q) {
      float v = acc[q] * rden;
      o[q] = (v > 0.0f) ? v : (__expf(v) - 1.0f);
    }
    if (WRITE_AC) {
      half8 hi;
#pragma unroll
      for (int q = 0; q < 8; ++q) hi[q] = (_Float16)o[q];
      *(half8*)(Ac + (size_t)i * FOUT + h * HID + d8) = hi;
    } else {
      float* ob = out + (size_t)i * FOUT + h * HID + d8;
      *(float4*)(ob)     = make_float4(o[0], o[1], o[2], o[3]);
      *(float4*)(ob + 4) = make_float4(o[4], o[5], o[6], o[7]);
    }
  }
}

// ---------------------------------------------------------------------------
extern "C" void kernel_launch(void* const* d_in, const int* in_sizes, int n_in,
                              void* d_out, int out_size, void* d_ws,
                              size_t ws_size, hipStream_t stream) {
  const float* features = (const float*)d_in[0];
  const float* adj      = (const float*)d_in[1];
  const float* W1  = (const float*)d_in[2];
  const float* a1s = (const float*)d_in[3];
  const float* a1d = (const float*)d_in[4];
  const float* W2  = (const float*)d_in[5];
  const float* a2s = (const float*)d_in[6];
  const float* a2d = (const float*)d_in[7];
  const float* W3  = (const float*)d_in[8];
  const float* a3s = (const float*)d_in[9];
  const float* a3d = (const float*)d_in[10];
  float* out = (float*)d_out;

  char* ws = (char*)d_ws;
  size_t off = 0;
  int* nbr_cnt = (int*)(ws + off); off += (size_t)NODES * 4;
  int* nbr     = (int*)(ws + off); off += (size_t)NODES * MAXNBR * 4;
  _Float16* Wh16 = (_Float16*)(ws + off); off += (size_t)NODES * FOUT * 2;
  float* sbuf  = (float*)(ws + off); off += (size_t)HEADS * NODES * 4;
  float* dbuf  = (float*)(ws + off); off += (size_t)HEADS * NODES * 4;
  _Float16* Ac1 = (_Float16*)(ws + off); off += (size_t)NODES * 256 * 2;   // layer-1 A (fp16)
  _Float16* Ac2 = (_Float16*)(ws + off); off += (size_t)NODES * FOUT * 2;  // layers 2/3 A
  _Float16* Bc1 = (_Float16*)(ws + off); off += (size_t)FOUT * 256 * 2;
  _Float16* Bc2 = (_Float16*)(ws + off); off += (size_t)FOUT * 512 * 2;
  _Float16* Bc3 = (_Float16*)(ws + off); off += (size_t)FOUT * 512 * 2;

  prep_kernel<<<2368, 256, 0, stream>>>(adj, nbr_cnt, nbr, features, Ac1,
                                        W1, W2, W3, Bc1, Bc2, Bc3);

  dim3 gg(HEADS, NODES / 64);

  // ---- layer 1 (Keff=256, plain fp16) ----
  gemm_mfma<<<gg, 256, 0, stream>>>(Ac1, Bc1, Wh16, a1s, a1d, sbuf, dbuf, 256);
  attn_kernel<1><<<NODES, 512, 0, stream>>>(nbr_cnt, nbr, sbuf, dbuf, Wh16, out, Ac2);
  // ---- layer 2 (Keff=512, plain fp16) ----
  gemm_mfma<<<gg, 256, 0, stream>>>(Ac2, Bc2, Wh16, a2s, a2d, sbuf, dbuf, 512);
  attn_kernel<1><<<NODES, 512, 0, stream>>>(nbr_cnt, nbr, sbuf, dbuf, Wh16, out, Ac2);
  // ---- layer 3 (Keff=512, plain fp16) ----
  gemm_mfma<<<gg, 256, 0, stream>>>(Ac2, Bc3, Wh16, a3s, a3d, sbuf, dbuf, 512);
  attn_kernel<0><<<NODES, 512, 0, stream>>>(nbr_cnt, nbr, sbuf, dbuf, Wh16, out, Ac2);
}

// Round 14
// 127.651 us; speedup vs baseline: 1.0004x; 1.0004x over previous
//
#include <hip/hip_runtime.h>
#include <hip/hip_bf16.h>
#include <math.h>

// GAT, 3 layers, N=4096, H=8, O=64, F_in=256 then 512.
// Sparse softmax over ~1%-dense adj (+self loops) is EXACT vs masked dense.
//
// R2-R8: MFMA GEMMs; fused prep/sd/convA; fp16 Wh gather everywhere.
// R9/R10: gemm1 plain fp16; prep grid fixed.
// R11/R12: 16-granularity gather + 1-deep software prefetch (115.9us).
// R13(this): gather issues a FULL 64-slot window of loads back-to-back
//     (8 independent 1KB wave-loads in flight vs 2) with uniform 16-slot
//     guards (same padded-load count as R12; cnt is block-uniform and
//     lst/w LDS are fully padded so extra slots are w=0 self-loops).
//     Rows with cnt>64 (expected ~0.6/4096) take a second window pass.

#define NODES 4096
#define HEADS 8
#define HID   64
#define FOUT  512   // HEADS*HID
#define MAXNBR 128

typedef _Float16 half8 __attribute__((ext_vector_type(8)));
typedef _Float16 half4 __attribute__((ext_vector_type(4)));
typedef float f32x4 __attribute__((ext_vector_type(4)));

// ---------------------------------------------------------------------------
// device helpers for the fused prep kernel
// ---------------------------------------------------------------------------
__device__ inline void conv_a_elem(const float* __restrict__ in,
                                   _Float16* __restrict__ out, int K, int id) {
  // plain fp16 A [4096][K]; id in [0, NODES*K/4)
  int perRow = K >> 2;
  int m = id / perRow, c = (id - m * perRow) * 4;
  float4 v = *(const float4*)(in + (size_t)m * K + c);
  half4 hi;
  hi[0] = (_Float16)v.x; hi[1] = (_Float16)v.y;
  hi[2] = (_Float16)v.z; hi[3] = (_Float16)v.w;
  *(half4*)(out + (size_t)m * K + c) = hi;
}

__device__ inline void conv_w_elem(const float* __restrict__ W,
                                   _Float16* __restrict__ Bc, int K, int id) {
  // plain fp16 B [512][K] (n-major); id in [0, HEADS*64*K/8)
  int n = id & 63;
  int r = id >> 6;
  int kchunks = K >> 3;
  int kc = r % kchunks, h = r / kchunks;
  int k0 = kc * 8;
  half8 hi;
#pragma unroll
  for (int i = 0; i < 8; ++i)
    hi[i] = (_Float16)W[((size_t)h * K + k0 + i) * 64 + n];
  *(half8*)(Bc + (size_t)(h * 64 + n) * K + k0) = hi;
}

// ---------------------------------------------------------------------------
// Fused prep: block-range partitioned. Element counts per range:
//   build_nbr: 4096 rows / 4 waves-per-block          -> 1024 blocks [0,1024)
//   convA:     4096*256/4 = 262144 f4-elems / 256 thr -> 1024 blocks [1024,2048)
//   convW1:    8*64*(256/8) = 16384 / 256             ->   64 blocks [2048,2112)
//   convW2:    8*64*(512/8) = 32768 / 256             ->  128 blocks [2112,2240)
//   convW3:    same                                    ->  128 blocks [2240,2368)
// ---------------------------------------------------------------------------
__global__ __launch_bounds__(256) void prep_kernel(
    const float* __restrict__ adj, int* __restrict__ nbr_cnt,
    int* __restrict__ nbr, const float* __restrict__ features,
    _Float16* __restrict__ Ac1,
    const float* __restrict__ W1, const float* __restrict__ W2,
    const float* __restrict__ W3, _Float16* __restrict__ Bc1,
    _Float16* __restrict__ Bc2, _Float16* __restrict__ Bc3) {
  const int b = blockIdx.x;
  if (b < 1024) {
    int wave = b * 4 + (threadIdx.x >> 6);
    int lane = threadIdx.x & 63;
    const float4* arow = (const float4*)(adj + (size_t)wave * NODES);
    int* lst = nbr + (size_t)wave * MAXNBR;
    int base = 0;
    float4 a0 = arow[lane];
    float4 a1 = arow[64 + lane];
#pragma unroll 4
    for (int it = 0; it < 16; ++it) {
      float4 cur = a0;
      a0 = a1;
      if (it + 2 < 16) a1 = arow[(it + 2) * 64 + lane];
      const int colbase = it * 256 + lane * 4;
#pragma unroll
      for (int c = 0; c < 4; ++c) {
        float v = (c == 0) ? cur.x : (c == 1) ? cur.y : (c == 2) ? cur.z : cur.w;
        unsigned long long mask = __ballot(v > 0.0f);
        if (v > 0.0f) {
          int pos = base + __popcll(mask & ((1ull << lane) - 1ull));
          if (pos < MAXNBR) lst[pos] = colbase + c;
        }
        base += __popcll(mask);
      }
    }
    if (lane == 0) nbr_cnt[wave] = base < MAXNBR ? base : MAXNBR;
  } else if (b < 2048) {
    conv_a_elem(features, Ac1, 256, (b - 1024) * 256 + threadIdx.x);
  } else if (b < 2112) {
    conv_w_elem(W1, Bc1, 256, (b - 2048) * 256 + threadIdx.x);
  } else if (b < 2240) {
    conv_w_elem(W2, Bc2, 512, (b - 2112) * 256 + threadIdx.x);
  } else {
    conv_w_elem(W3, Bc3, 512, (b - 2240) * 256 + threadIdx.x);
  }
}

// ---------------------------------------------------------------------------
// C16[4096,512] = A[4096,Keff] * B[512,Keff]^T (fp16 in, fp32 accum, fp16 out)
// 64x64 tile, BK=32, 4 waves, 2x2 frags of 16x16x32 MFMA.
// Fused epilogue: s[h,m], d[h,m] computed fp32-exact from accumulators.
// ---------------------------------------------------------------------------
__global__ __launch_bounds__(256) void gemm_mfma(
    const _Float16* __restrict__ A,   // [4096][Keff]
    const _Float16* __restrict__ B,   // [512][Keff]  (n-major)
    _Float16* __restrict__ C16,       // [4096][512]
    const float* __restrict__ a_src,  // [8][64]
    const float* __restrict__ a_dst,  // [8][64]
    float* __restrict__ sbuf,         // [8][4096]
    float* __restrict__ dbuf,         // [8][4096]
    int Keff) {
  __shared__ _Float16 As[64 * 40];
  __shared__ _Float16 Bs[64 * 40];
  __shared__ float sS[2][64];
  __shared__ float sD[2][64];

  const int t    = threadIdx.x;
  const int m0   = blockIdx.y * 64;
  const int n0   = blockIdx.x * 64;
  const int h    = blockIdx.x;
  const int w    = t >> 6;
  const int lane = t & 63;
  const int wr   = (w >> 1) * 32;
  const int wc   = (w & 1) * 32;
  const int lr   = lane & 15;
  const int lk   = (lane >> 4) * 8;

  const int sr = t >> 2;
  const int sc = (t & 3) * 8;
  const _Float16* gA = A + (size_t)(m0 + sr) * Keff + sc;
  const _Float16* gB = B + (size_t)(n0 + sr) * Keff + sc;

  f32x4 acc00 = {}, acc01 = {}, acc10 = {}, acc11 = {};

  half8 av = *(const half8*)(gA);
  half8 bv = *(const half8*)(gB);

  for (int k0 = 0; k0 < Keff; k0 += 32) {
    __syncthreads();
    *(half8*)(&As[sr * 40 + sc]) = av;
    *(half8*)(&Bs[sr * 40 + sc]) = bv;
    __syncthreads();
    if (k0 + 32 < Keff) {
      av = *(const half8*)(gA + k0 + 32);
      bv = *(const half8*)(gB + k0 + 32);
    }
    half8 a0 = *(const half8*)(&As[(wr + lr) * 40 + lk]);
    half8 a1 = *(const half8*)(&As[(wr + 16 + lr) * 40 + lk]);
    half8 b0 = *(const half8*)(&Bs[(wc + lr) * 40 + lk]);
    half8 b1 = *(const half8*)(&Bs[(wc + 16 + lr) * 40 + lk]);
    acc00 = __builtin_amdgcn_mfma_f32_16x16x32_f16(a0, b0, acc00, 0, 0, 0);
    acc01 = __builtin_amdgcn_mfma_f32_16x16x32_f16(a0, b1, acc01, 0, 0, 0);
    acc10 = __builtin_amdgcn_mfma_f32_16x16x32_f16(a1, b0, acc10, 0, 0, 0);
    acc11 = __builtin_amdgcn_mfma_f32_16x16x32_f16(a1, b1, acc11, 0, 0, 0);
  }

  // C/D layout: col = lane&15, row = (lane>>4)*4 + reg  [m89/m91 verified]
  const int cm = (lane >> 4) * 4;
#pragma unroll
  for (int j = 0; j < 4; ++j) {
    int m  = m0 + wr + cm + j;
    int m2 = m + 16;
    C16[(size_t)m * FOUT + n0 + wc + lr]       = (_Float16)acc00[j];
    C16[(size_t)m * FOUT + n0 + wc + 16 + lr]  = (_Float16)acc01[j];
    C16[(size_t)m2 * FOUT + n0 + wc + lr]      = (_Float16)acc10[j];
    C16[(size_t)m2 * FOUT + n0 + wc + 16 + lr] = (_Float16)acc11[j];
  }

  // fused s/d epilogue (fp32-exact from accumulators)
  const float as0 = a_src[(h << 6) + wc + lr];
  const float as1 = a_src[(h << 6) + wc + 16 + lr];
  const float ad0 = a_dst[(h << 6) + wc + lr];
  const float ad1 = a_dst[(h << 6) + wc + 16 + lr];
  float ps[8], pd[8];
#pragma unroll
  for (int j = 0; j < 4; ++j) {
    ps[j]     = acc00[j] * as0 + acc01[j] * as1;
    ps[4 + j] = acc10[j] * as0 + acc11[j] * as1;
    pd[j]     = acc00[j] * ad0 + acc01[j] * ad1;
    pd[4 + j] = acc10[j] * ad0 + acc11[j] * ad1;
  }
#pragma unroll
  for (int off = 1; off < 16; off <<= 1) {
#pragma unroll
    for (int j = 0; j < 8; ++j) {
      ps[j] += __shfl_xor(ps[j], off);
      pd[j] += __shfl_xor(pd[j], off);
    }
  }
  if (lr == 0) {
#pragma unroll
    for (int j = 0; j < 4; ++j) {
      sS[w & 1][wr + cm + j]      = ps[j];
      sS[w & 1][wr + 16 + cm + j] = ps[4 + j];
      sD[w & 1][wr + cm + j]      = pd[j];
      sD[w & 1][wr + 16 + cm + j] = pd[4 + j];
    }
  }
  __syncthreads();
  if (t < 64) {
    sbuf[(size_t)h * NODES + m0 + t] = sS[0][t] + sS[1][t];
    dbuf[(size_t)h * NODES + m0 + t] = sD[0][t] + sD[1][t];
  }
}

// ---------------------------------------------------------------------------
// Sparse masked softmax + PV + ELU. fp16 Wh16 gather: one 64-slot window of
// up to 8 wave-loads issued back-to-back (uniform 16-slot guards), then FMAs.
// cnt is block-uniform; lst/w LDS fully padded (self, w=0) -> guards exact.
// WRITE_AC=1: write next layer's A as fp16 [4096][512]. =0: fp32 out.
// ---------------------------------------------------------------------------
template <int WRITE_AC>
__global__ __launch_bounds__(512) void attn_kernel(
    const int* __restrict__ nbr_cnt, const int* __restrict__ nbr,
    const float* __restrict__ s, const float* __restrict__ d,
    const _Float16* __restrict__ Wh16,
    float* __restrict__ out, _Float16* __restrict__ Ac) {
  __shared__ int   lst_lds[MAXNBR];
  __shared__ float w_lds[HEADS][MAXNBR];

  const int i    = blockIdx.x;
  const int tid  = threadIdx.x;
  const int h    = tid >> 6;
  const int lane = tid & 63;
  const int cnt  = nbr_cnt[i];

  if (tid < MAXNBR)
    lst_lds[tid] = (tid < cnt) ? nbr[(size_t)i * MAXNBR + tid] : i;
  __syncthreads();

  const float s_i = s[(size_t)h * NODES + i];
  const float* dh = d + (size_t)h * NODES;
  float e0 = -1e30f, e1 = -1e30f;
  if (lane < cnt) {
    float e = s_i + dh[lst_lds[lane]];
    e0 = (e >= 0.0f) ? e : 0.2f * e;
  }
  if (lane + 64 < cnt) {
    float e = s_i + dh[lst_lds[lane + 64]];
    e1 = (e >= 0.0f) ? e : 0.2f * e;
  }
  float m = fmaxf(e0, e1);
#pragma unroll
  for (int off = 32; off; off >>= 1) m = fmaxf(m, __shfl_xor(m, off));
  float w0 = (lane < cnt) ? __expf(e0 - m) : 0.0f;
  float w1 = (lane + 64 < cnt) ? __expf(e1 - m) : 0.0f;
  w_lds[h][lane]      = w0;
  w_lds[h][lane + 64] = w1;
  float den = w0 + w1;
#pragma unroll
  for (int off = 32; off; off >>= 1) den += __shfl_xor(den, off);
  const float rden = 1.0f / den;
  __syncthreads();

  // gather: 8 subgroups of 8 lanes; lane covers 8 dims via half8.
  const int g  = lane >> 3;
  const int d8 = (lane & 7) * 8;
  const int cnt16 = (cnt + 15) & ~15;
  const _Float16* base = Wh16 + h * HID + d8;
  float aA[8] = {}, aB[8] = {};

  for (int t0 = 0; t0 < cnt16; t0 += 64) {     // one pass for cnt<=64 (~all)
    const int rem = cnt16 - t0;                // multiple of 16, >= 16
    half8 vA0, vB0, vA1, vB1, vA2, vB2, vA3, vB3;
    float wA0, wB0, wA1, wB1, wA2, wB2, wA3, wB3;
    // ---- issue all loads back-to-back (uniform guards) ----
    {
      const int ta = t0 + g, tb = ta + 8;
      wA0 = w_lds[h][ta]; wB0 = w_lds[h][tb];
      vA0 = *(const half8*)(base + (size_t)lst_lds[ta] * FOUT);
      vB0 = *(const half8*)(base + (size_t)lst_lds[tb] * FOUT);
    }
    if (rem > 16) {
      const int ta = t0 + 16 + g, tb = ta + 8;
      wA1 = w_lds[h][ta]; wB1 = w_lds[h][tb];
      vA1 = *(const half8*)(base + (size_t)lst_lds[ta] * FOUT);
      vB1 = *(const half8*)(base + (size_t)lst_lds[tb] * FOUT);
    }
    if (rem > 32) {
      const int ta = t0 + 32 + g, tb = ta + 8;
      wA2 = w_lds[h][ta]; wB2 = w_lds[h][tb];
      vA2 = *(const half8*)(base + (size_t)lst_lds[ta] * FOUT);
      vB2 = *(const half8*)(base + (size_t)lst_lds[tb] * FOUT);
    }
    if (rem > 48) {
      const int ta = t0 + 48 + g, tb = ta + 8;
      wA3 = w_lds[h][ta]; wB3 = w_lds[h][tb];
      vA3 = *(const half8*)(base + (size_t)lst_lds[ta] * FOUT);
      vB3 = *(const half8*)(base + (size_t)lst_lds[tb] * FOUT);
    }
    // ---- accumulate ----
#pragma unroll
    for (int q = 0; q < 8; ++q) {
      aA[q] += wA0 * (float)vA0[q];
      aB[q] += wB0 * (float)vB0[q];
    }
    if (rem > 16) {
#pragma unroll
      for (int q = 0; q < 8; ++q) {
        aA[q] += wA1 * (float)vA1[q];
        aB[q] += wB1 * (float)vB1[q];
      }
    }
    if (rem > 32) {
#pragma unroll
      for (int q = 0; q < 8; ++q) {
        aA[q] += wA2 * (float)vA2[q];
        aB[q] += wB2 * (float)vB2[q];
      }
    }
    if (rem > 48) {
#pragma unroll
      for (int q = 0; q < 8; ++q) {
        aA[q] += wA3 * (float)vA3[q];
        aB[q] += wB3 * (float)vB3[q];
      }
    }
  }

  float acc[8];
#pragma unroll
  for (int q = 0; q < 8; ++q) acc[q] = aA[q] + aB[q];
#pragma unroll
  for (int off = 8; off <= 32; off <<= 1)
#pragma unroll
    for (int q = 0; q < 8; ++q) acc[q] += __shfl_xor(acc[q], off);

  if (lane < 8) {
    float o[8];
#pragma unroll
    for (int q = 0; q < 8; ++q) {
      float v = acc[q] * rden;
      o[q] = (v > 0.0f) ? v : (__expf(v) - 1.0f);
    }
    if (WRITE_AC) {
      half8 hi;
#pragma unroll
      for (int q = 0; q < 8; ++q) hi[q] = (_Float16)o[q];
      *(half8*)(Ac + (size_t)i * FOUT + h * HID + d8) = hi;
    } else {
      float* ob = out + (size_t)i * FOUT + h * HID + d8;
      *(float4*)(ob)     = make_float4(o[0], o[1], o[2], o[3]);
      *(float4*)(ob + 4) = make_float4(o[4], o[5], o[6], o[7]);
    }
  }
}

// ---------------------------------------------------------------------------
extern "C" void kernel_launch(void* const* d_in, const int* in_sizes, int n_in,
                              void* d_out, int out_size, void* d_ws,
                              size_t ws_size, hipStream_t stream) {
  const float* features = (const float*)d_in[0];
  const float* adj      = (const float*)d_in[1];
  const float* W1  = (const float*)d_in[2];
  const float* a1s = (const float*)d_in[3];
  const float* a1d = (const float*)d_in[4];
  const float* W2  = (const float*)d_in[5];
  const float* a2s = (const float*)d_in[6];
  const float* a2d = (const float*)d_in[7];
  const float* W3  = (const float*)d_in[8];
  const float* a3s = (const float*)d_in[9];
  const float* a3d = (const float*)d_in[10];
  float* out = (float*)d_out;

  char* ws = (char*)d_ws;
  size_t off = 0;
  int* nbr_cnt = (int*)(ws + off); off += (size_t)NODES * 4;
  int* nbr     = (int*)(ws + off); off += (size_t)NODES * MAXNBR * 4;
  _Float16* Wh16 = (_Float16*)(ws + off); off += (size_t)NODES * FOUT * 2;
  float* sbuf  = (float*)(ws + off); off += (size_t)HEADS * NODES * 4;
  float* dbuf  = (float*)(ws + off); off += (size_t)HEADS * NODES * 4;
  _Float16* Ac1 = (_Float16*)(ws + off); off += (size_t)NODES * 256 * 2;   // layer-1 A (fp16)
  _Float16* Ac2 = (_Float16*)(ws + off); off += (size_t)NODES * FOUT * 2;  // layers 2/3 A
  _Float16* Bc1 = (_Float16*)(ws + off); off += (size_t)FOUT * 256 * 2;
  _Float16* Bc2 = (_Float16*)(ws + off); off += (size_t)FOUT * 512 * 2;
  _Float16* Bc3 = (_Float16*)(ws + off); off += (size_t)FOUT * 512 * 2;

  prep_kernel<<<2368, 256, 0, stream>>>(adj, nbr_cnt, nbr, features, Ac1,
                                        W1, W2, W3, Bc1, Bc2, Bc3);

  dim3 gg(HEADS, NODES / 64);

  // ---- layer 1 (Keff=256, plain fp16) ----
  gemm_mfma<<<gg, 256, 0, stream>>>(Ac1, Bc1, Wh16, a1s, a1d, sbuf, dbuf, 256);
  attn_kernel<1><<<NODES, 512, 0, stream>>>(nbr_cnt, nbr, sbuf, dbuf, Wh16, out, Ac2);
  // ---- layer 2 (Keff=512, plain fp16) ----
  gemm_mfma<<<gg, 256, 0, stream>>>(Ac2, Bc2, Wh16, a2s, a2d, sbuf, dbuf, 512);
  attn_kernel<1><<<NODES, 512, 0, stream>>>(nbr_cnt, nbr, sbuf, dbuf, Wh16, out, Ac2);
  // ---- layer 3 (Keff=512, plain fp16) ----
  gemm_mfma<<<gg, 256, 0, stream>>>(Ac2, Bc3, Wh16, a3s, a3d, sbuf, dbuf, 512);
  attn_kernel<0><<<NODES, 512, 0, stream>>>(nbr_cnt, nbr, sbuf, dbuf, Wh16, out, Ac2);
}

// Round 15
// 123.796 us; speedup vs baseline: 1.0316x; 1.0311x over previous
//
#include <hip/hip_runtime.h>
#include <hip/hip_bf16.h>
#include <math.h>

// GAT, 3 layers, N=4096, H=8, O=64, F_in=256 then 512.
// Sparse softmax over ~1%-dense adj (+self loops) is EXACT vs masked dense.
//
// R2-R12: MFMA GEMMs (plain fp16 everywhere); fused prep/sd; fp16 Wh gather,
//   16-slot windows + 1-deep prefetch (115.9us best).
// R13: 64-slot branchy window -> REGRESSION (branches serialize load issue).
// R14(this): R12 gather + 2-deep SKEWED pipeline: prologue issues windows
//   0,1 back-to-back (4 loads in flight, straight-line); loop loads window k
//   while FMA-ing window k-2; branch only on nw>1 (uniform, once).

#define NODES 4096
#define HEADS 8
#define HID   64
#define FOUT  512   // HEADS*HID
#define MAXNBR 128

typedef _Float16 half8 __attribute__((ext_vector_type(8)));
typedef _Float16 half4 __attribute__((ext_vector_type(4)));
typedef float f32x4 __attribute__((ext_vector_type(4)));

// ---------------------------------------------------------------------------
// device helpers for the fused prep kernel
// ---------------------------------------------------------------------------
__device__ inline void conv_a_elem(const float* __restrict__ in,
                                   _Float16* __restrict__ out, int K, int id) {
  // plain fp16 A [4096][K]; id in [0, NODES*K/4)
  int perRow = K >> 2;
  int m = id / perRow, c = (id - m * perRow) * 4;
  float4 v = *(const float4*)(in + (size_t)m * K + c);
  half4 hi;
  hi[0] = (_Float16)v.x; hi[1] = (_Float16)v.y;
  hi[2] = (_Float16)v.z; hi[3] = (_Float16)v.w;
  *(half4*)(out + (size_t)m * K + c) = hi;
}

__device__ inline void conv_w_elem(const float* __restrict__ W,
                                   _Float16* __restrict__ Bc, int K, int id) {
  // plain fp16 B [512][K] (n-major); id in [0, HEADS*64*K/8)
  int n = id & 63;
  int r = id >> 6;
  int kchunks = K >> 3;
  int kc = r % kchunks, h = r / kchunks;
  int k0 = kc * 8;
  half8 hi;
#pragma unroll
  for (int i = 0; i < 8; ++i)
    hi[i] = (_Float16)W[((size_t)h * K + k0 + i) * 64 + n];
  *(half8*)(Bc + (size_t)(h * 64 + n) * K + k0) = hi;
}

// ---------------------------------------------------------------------------
// Fused prep: block-range partitioned. Element counts per range:
//   build_nbr: 4096 rows / 4 waves-per-block          -> 1024 blocks [0,1024)
//   convA:     4096*256/4 = 262144 f4-elems / 256 thr -> 1024 blocks [1024,2048)
//   convW1:    8*64*(256/8) = 16384 / 256             ->   64 blocks [2048,2112)
//   convW2:    8*64*(512/8) = 32768 / 256             ->  128 blocks [2112,2240)
//   convW3:    same                                    ->  128 blocks [2240,2368)
// ---------------------------------------------------------------------------
__global__ __launch_bounds__(256) void prep_kernel(
    const float* __restrict__ adj, int* __restrict__ nbr_cnt,
    int* __restrict__ nbr, const float* __restrict__ features,
    _Float16* __restrict__ Ac1,
    const float* __restrict__ W1, const float* __restrict__ W2,
    const float* __restrict__ W3, _Float16* __restrict__ Bc1,
    _Float16* __restrict__ Bc2, _Float16* __restrict__ Bc3) {
  const int b = blockIdx.x;
  if (b < 1024) {
    int wave = b * 4 + (threadIdx.x >> 6);
    int lane = threadIdx.x & 63;
    const float4* arow = (const float4*)(adj + (size_t)wave * NODES);
    int* lst = nbr + (size_t)wave * MAXNBR;
    int base = 0;
    float4 a0 = arow[lane];
    float4 a1 = arow[64 + lane];
#pragma unroll 4
    for (int it = 0; it < 16; ++it) {
      float4 cur = a0;
      a0 = a1;
      if (it + 2 < 16) a1 = arow[(it + 2) * 64 + lane];
      const int colbase = it * 256 + lane * 4;
#pragma unroll
      for (int c = 0; c < 4; ++c) {
        float v = (c == 0) ? cur.x : (c == 1) ? cur.y : (c == 2) ? cur.z : cur.w;
        unsigned long long mask = __ballot(v > 0.0f);
        if (v > 0.0f) {
          int pos = base + __popcll(mask & ((1ull << lane) - 1ull));
          if (pos < MAXNBR) lst[pos] = colbase + c;
        }
        base += __popcll(mask);
      }
    }
    if (lane == 0) nbr_cnt[wave] = base < MAXNBR ? base : MAXNBR;
  } else if (b < 2048) {
    conv_a_elem(features, Ac1, 256, (b - 1024) * 256 + threadIdx.x);
  } else if (b < 2112) {
    conv_w_elem(W1, Bc1, 256, (b - 2048) * 256 + threadIdx.x);
  } else if (b < 2240) {
    conv_w_elem(W2, Bc2, 512, (b - 2112) * 256 + threadIdx.x);
  } else {
    conv_w_elem(W3, Bc3, 512, (b - 2240) * 256 + threadIdx.x);
  }
}

// ---------------------------------------------------------------------------
// C16[4096,512] = A[4096,Keff] * B[512,Keff]^T (fp16 in, fp32 accum, fp16 out)
// 64x64 tile, BK=32, 4 waves, 2x2 frags of 16x16x32 MFMA.
// Fused epilogue: s[h,m], d[h,m] computed fp32-exact from accumulators.
// ---------------------------------------------------------------------------
__global__ __launch_bounds__(256) void gemm_mfma(
    const _Float16* __restrict__ A,   // [4096][Keff]
    const _Float16* __restrict__ B,   // [512][Keff]  (n-major)
    _Float16* __restrict__ C16,       // [4096][512]
    const float* __restrict__ a_src,  // [8][64]
    const float* __restrict__ a_dst,  // [8][64]
    float* __restrict__ sbuf,         // [8][4096]
    float* __restrict__ dbuf,         // [8][4096]
    int Keff) {
  __shared__ _Float16 As[64 * 40];
  __shared__ _Float16 Bs[64 * 40];
  __shared__ float sS[2][64];
  __shared__ float sD[2][64];

  const int t    = threadIdx.x;
  const int m0   = blockIdx.y * 64;
  const int n0   = blockIdx.x * 64;
  const int h    = blockIdx.x;
  const int w    = t >> 6;
  const int lane = t & 63;
  const int wr   = (w >> 1) * 32;
  const int wc   = (w & 1) * 32;
  const int lr   = lane & 15;
  const int lk   = (lane >> 4) * 8;

  const int sr = t >> 2;
  const int sc = (t & 3) * 8;
  const _Float16* gA = A + (size_t)(m0 + sr) * Keff + sc;
  const _Float16* gB = B + (size_t)(n0 + sr) * Keff + sc;

  f32x4 acc00 = {}, acc01 = {}, acc10 = {}, acc11 = {};

  half8 av = *(const half8*)(gA);
  half8 bv = *(const half8*)(gB);

  for (int k0 = 0; k0 < Keff; k0 += 32) {
    __syncthreads();
    *(half8*)(&As[sr * 40 + sc]) = av;
    *(half8*)(&Bs[sr * 40 + sc]) = bv;
    __syncthreads();
    if (k0 + 32 < Keff) {
      av = *(const half8*)(gA + k0 + 32);
      bv = *(const half8*)(gB + k0 + 32);
    }
    half8 a0 = *(const half8*)(&As[(wr + lr) * 40 + lk]);
    half8 a1 = *(const half8*)(&As[(wr + 16 + lr) * 40 + lk]);
    half8 b0 = *(const half8*)(&Bs[(wc + lr) * 40 + lk]);
    half8 b1 = *(const half8*)(&Bs[(wc + 16 + lr) * 40 + lk]);
    acc00 = __builtin_amdgcn_mfma_f32_16x16x32_f16(a0, b0, acc00, 0, 0, 0);
    acc01 = __builtin_amdgcn_mfma_f32_16x16x32_f16(a0, b1, acc01, 0, 0, 0);
    acc10 = __builtin_amdgcn_mfma_f32_16x16x32_f16(a1, b0, acc10, 0, 0, 0);
    acc11 = __builtin_amdgcn_mfma_f32_16x16x32_f16(a1, b1, acc11, 0, 0, 0);
  }

  // C/D layout: col = lane&15, row = (lane>>4)*4 + reg  [m89/m91 verified]
  const int cm = (lane >> 4) * 4;
#pragma unroll
  for (int j = 0; j < 4; ++j) {
    int m  = m0 + wr + cm + j;
    int m2 = m + 16;
    C16[(size_t)m * FOUT + n0 + wc + lr]       = (_Float16)acc00[j];
    C16[(size_t)m * FOUT + n0 + wc + 16 + lr]  = (_Float16)acc01[j];
    C16[(size_t)m2 * FOUT + n0 + wc + lr]      = (_Float16)acc10[j];
    C16[(size_t)m2 * FOUT + n0 + wc + 16 + lr] = (_Float16)acc11[j];
  }

  // fused s/d epilogue (fp32-exact from accumulators)
  const float as0 = a_src[(h << 6) + wc + lr];
  const float as1 = a_src[(h << 6) + wc + 16 + lr];
  const float ad0 = a_dst[(h << 6) + wc + lr];
  const float ad1 = a_dst[(h << 6) + wc + 16 + lr];
  float ps[8], pd[8];
#pragma unroll
  for (int j = 0; j < 4; ++j) {
    ps[j]     = acc00[j] * as0 + acc01[j] * as1;
    ps[4 + j] = acc10[j] * as0 + acc11[j] * as1;
    pd[j]     = acc00[j] * ad0 + acc01[j] * ad1;
    pd[4 + j] = acc10[j] * ad0 + acc11[j] * ad1;
  }
#pragma unroll
  for (int off = 1; off < 16; off <<= 1) {
#pragma unroll
    for (int j = 0; j < 8; ++j) {
      ps[j] += __shfl_xor(ps[j], off);
      pd[j] += __shfl_xor(pd[j], off);
    }
  }
  if (lr == 0) {
#pragma unroll
    for (int j = 0; j < 4; ++j) {
      sS[w & 1][wr + cm + j]      = ps[j];
      sS[w & 1][wr + 16 + cm + j] = ps[4 + j];
      sD[w & 1][wr + cm + j]      = pd[j];
      sD[w & 1][wr + 16 + cm + j] = pd[4 + j];
    }
  }
  __syncthreads();
  if (t < 64) {
    sbuf[(size_t)h * NODES + m0 + t] = sS[0][t] + sS[1][t];
    dbuf[(size_t)h * NODES + m0 + t] = sD[0][t] + sD[1][t];
  }
}

// ---------------------------------------------------------------------------
// Sparse masked softmax + PV + ELU. fp16 Wh16 gather, 16-slot windows,
// 2-deep skewed pipeline: load window k while FMA-ing window k-2.
// WRITE_AC=1: write next layer's A as fp16 [4096][512]. =0: fp32 out.
// ---------------------------------------------------------------------------
template <int WRITE_AC>
__global__ __launch_bounds__(512) void attn_kernel(
    const int* __restrict__ nbr_cnt, const int* __restrict__ nbr,
    const float* __restrict__ s, const float* __restrict__ d,
    const _Float16* __restrict__ Wh16,
    float* __restrict__ out, _Float16* __restrict__ Ac) {
  __shared__ int   lst_lds[MAXNBR];
  __shared__ float w_lds[HEADS][MAXNBR];

  const int i    = blockIdx.x;
  const int tid  = threadIdx.x;
  const int h    = tid >> 6;
  const int lane = tid & 63;
  const int cnt  = nbr_cnt[i];

  if (tid < MAXNBR)
    lst_lds[tid] = (tid < cnt) ? nbr[(size_t)i * MAXNBR + tid] : i;
  __syncthreads();

  const float s_i = s[(size_t)h * NODES + i];
  const float* dh = d + (size_t)h * NODES;
  float e0 = -1e30f, e1 = -1e30f;
  if (lane < cnt) {
    float e = s_i + dh[lst_lds[lane]];
    e0 = (e >= 0.0f) ? e : 0.2f * e;
  }
  if (lane + 64 < cnt) {
    float e = s_i + dh[lst_lds[lane + 64]];
    e1 = (e >= 0.0f) ? e : 0.2f * e;
  }
  float m = fmaxf(e0, e1);
#pragma unroll
  for (int off = 32; off; off >>= 1) m = fmaxf(m, __shfl_xor(m, off));
  float w0 = (lane < cnt) ? __expf(e0 - m) : 0.0f;
  float w1 = (lane + 64 < cnt) ? __expf(e1 - m) : 0.0f;
  w_lds[h][lane]      = w0;
  w_lds[h][lane + 64] = w1;
  float den = w0 + w1;
#pragma unroll
  for (int off = 32; off; off >>= 1) den += __shfl_xor(den, off);
  const float rden = 1.0f / den;
  __syncthreads();

  // gather: 8 subgroups of 8 lanes; lane covers 8 dims via half8.
  // 16-slot windows; 2-deep skewed pipeline (4 loads in flight, no branches
  // between the prologue loads).
  const int g  = lane >> 3;
  const int d8 = (lane & 7) * 8;
  const int nw = ((cnt + 15) & ~15) >> 4;   // #windows, >= 1
  const _Float16* base = Wh16 + h * HID + d8;
  float aA[8] = {}, aB[8] = {};

  float wa0, wb0, wa1 = 0.f, wb1 = 0.f;
  half8 va0, vb0, va1 = {}, vb1 = {};
  {
    const int ta = g, tb = g + 8;
    wa0 = w_lds[h][ta]; wb0 = w_lds[h][tb];
    va0 = *(const half8*)(base + (size_t)lst_lds[ta] * FOUT);
    vb0 = *(const half8*)(base + (size_t)lst_lds[tb] * FOUT);
  }
  if (nw > 1) {
    const int ta = 16 + g, tb = ta + 8;
    wa1 = w_lds[h][ta]; wb1 = w_lds[h][tb];
    va1 = *(const half8*)(base + (size_t)lst_lds[ta] * FOUT);
    vb1 = *(const half8*)(base + (size_t)lst_lds[tb] * FOUT);
  }
  for (int k = 2; k < nw; ++k) {
    const int ta = k * 16 + g, tb = ta + 8;
    const float wa2 = w_lds[h][ta], wb2 = w_lds[h][tb];
    const half8 va2 = *(const half8*)(base + (size_t)lst_lds[ta] * FOUT);
    const half8 vb2 = *(const half8*)(base + (size_t)lst_lds[tb] * FOUT);
#pragma unroll
    for (int q = 0; q < 8; ++q) {
      aA[q] += wa0 * (float)va0[q];
      aB[q] += wb0 * (float)vb0[q];
    }
    wa0 = wa1; wb0 = wb1; va0 = va1; vb0 = vb1;
    wa1 = wa2; wb1 = wb2; va1 = va2; vb1 = vb2;
  }
#pragma unroll
  for (int q = 0; q < 8; ++q) {
    aA[q] += wa0 * (float)va0[q];
    aB[q] += wb0 * (float)vb0[q];
  }
  if (nw > 1) {
#pragma unroll
    for (int q = 0; q < 8; ++q) {
      aA[q] += wa1 * (float)va1[q];
      aB[q] += wb1 * (float)vb1[q];
    }
  }

  float acc[8];
#pragma unroll
  for (int q = 0; q < 8; ++q) acc[q] = aA[q] + aB[q];
#pragma unroll
  for (int off = 8; off <= 32; off <<= 1)
#pragma unroll
    for (int q = 0; q < 8; ++q) acc[q] += __shfl_xor(acc[q], off);

  if (lane < 8) {
    float o[8];
#pragma unroll
    for (int q = 0; q < 8; ++q) {
      float v = acc[q] * rden;
      o[q] = (v > 0.0f) ? v : (__expf(v) - 1.0f);
    }
    if (WRITE_AC) {
      half8 hi;
#pragma unroll
      for (int q = 0; q < 8; ++q) hi[q] = (_Float16)o[q];
      *(half8*)(Ac + (size_t)i * FOUT + h * HID + d8) = hi;
    } else {
      float* ob = out + (size_t)i * FOUT + h * HID + d8;
      *(float4*)(ob)     = make_float4(o[0], o[1], o[2], o[3]);
      *(float4*)(ob + 4) = make_float4(o[4], o[5], o[6], o[7]);
    }
  }
}

// ---------------------------------------------------------------------------
extern "C" void kernel_launch(void* const* d_in, const int* in_sizes, int n_in,
                              void* d_out, int out_size, void* d_ws,
                              size_t ws_size, hipStream_t stream) {
  const float* features = (const float*)d_in[0];
  const float* adj      = (const float*)d_in[1];
  const float* W1  = (const float*)d_in[2];
  const float* a1s = (const float*)d_in[3];
  const float* a1d = (const float*)d_in[4];
  const float* W2  = (const float*)d_in[5];
  const float* a2s = (const float*)d_in[6];
  const float* a2d = (const float*)d_in[7];
  const float* W3  = (const float*)d_in[8];
  const float* a3s = (const float*)d_in[9];
  const float* a3d = (const float*)d_in[10];
  float* out = (float*)d_out;

  char* ws = (char*)d_ws;
  size_t off = 0;
  int* nbr_cnt = (int*)(ws + off); off += (size_t)NODES * 4;
  int* nbr     = (int*)(ws + off); off += (size_t)NODES * MAXNBR * 4;
  _Float16* Wh16 = (_Float16*)(ws + off); off += (size_t)NODES * FOUT * 2;
  float* sbuf  = (float*)(ws + off); off += (size_t)HEADS * NODES * 4;
  float* dbuf  = (float*)(ws + off); off += (size_t)HEADS * NODES * 4;
  _Float16* Ac1 = (_Float16*)(ws + off); off += (size_t)NODES * 256 * 2;   // layer-1 A (fp16)
  _Float16* Ac2 = (_Float16*)(ws + off); off += (size_t)NODES * FOUT * 2;  // layers 2/3 A
  _Float16* Bc1 = (_Float16*)(ws + off); off += (size_t)FOUT * 256 * 2;
  _Float16* Bc2 = (_Float16*)(ws + off); off += (size_t)FOUT * 512 * 2;
  _Float16* Bc3 = (_Float16*)(ws + off); off += (size_t)FOUT * 512 * 2;

  prep_kernel<<<2368, 256, 0, stream>>>(adj, nbr_cnt, nbr, features, Ac1,
                                        W1, W2, W3, Bc1, Bc2, Bc3);

  dim3 gg(HEADS, NODES / 64);

  // ---- layer 1 (Keff=256, plain fp16) ----
  gemm_mfma<<<gg, 256, 0, stream>>>(Ac1, Bc1, Wh16, a1s, a1d, sbuf, dbuf, 256);
  attn_kernel<1><<<NODES, 512, 0, stream>>>(nbr_cnt, nbr, sbuf, dbuf, Wh16, out, Ac2);
  // ---- layer 2 (Keff=512, plain fp16) ----
  gemm_mfma<<<gg, 256, 0, stream>>>(Ac2, Bc2, Wh16, a2s, a2d, sbuf, dbuf, 512);
  attn_kernel<1><<<NODES, 512, 0, stream>>>(nbr_cnt, nbr, sbuf, dbuf, Wh16, out, Ac2);
  // ---- layer 3 (Keff=512, plain fp16) ----
  gemm_mfma<<<gg, 256, 0, stream>>>(Ac2, Bc3, Wh16, a3s, a3d, sbuf, dbuf, 512);
  attn_kernel<0><<<NODES, 512, 0, stream>>>(nbr_cnt, nbr, sbuf, dbuf, Wh16, out, Ac2);
}

// Round 16
// 117.921 us; speedup vs baseline: 1.0830x; 1.0498x over previous
//
#include <hip/hip_runtime.h>
#include <hip/hip_bf16.h>
#include <math.h>

// GAT, 3 layers, N=4096, H=8, O=64, F_in=256 then 512.
// Sparse softmax over ~1%-dense adj (+self loops) is EXACT vs masked dense.
//
// R2-R12: MFMA GEMMs (plain fp16 everywhere); fused prep/sd; fp16 Wh gather,
//   16-slot windows + 1-deep prefetch (115.9us best).
// R13/R14: deeper pipelines (branchy 64-slot; 2-deep skew) BOTH regressed —
//   trip count ~3 windows means depth>1 is pure prologue/epilogue overhead.
// R15(this): revert gather to R12 exactly; add s_setprio(1) around the
//   gather region (8 independent waves/block, no barrier -> m191 attn case).

#define NODES 4096
#define HEADS 8
#define HID   64
#define FOUT  512   // HEADS*HID
#define MAXNBR 128

typedef _Float16 half8 __attribute__((ext_vector_type(8)));
typedef _Float16 half4 __attribute__((ext_vector_type(4)));
typedef float f32x4 __attribute__((ext_vector_type(4)));

// ---------------------------------------------------------------------------
// device helpers for the fused prep kernel
// ---------------------------------------------------------------------------
__device__ inline void conv_a_elem(const float* __restrict__ in,
                                   _Float16* __restrict__ out, int K, int id) {
  // plain fp16 A [4096][K]; id in [0, NODES*K/4)
  int perRow = K >> 2;
  int m = id / perRow, c = (id - m * perRow) * 4;
  float4 v = *(const float4*)(in + (size_t)m * K + c);
  half4 hi;
  hi[0] = (_Float16)v.x; hi[1] = (_Float16)v.y;
  hi[2] = (_Float16)v.z; hi[3] = (_Float16)v.w;
  *(half4*)(out + (size_t)m * K + c) = hi;
}

__device__ inline void conv_w_elem(const float* __restrict__ W,
                                   _Float16* __restrict__ Bc, int K, int id) {
  // plain fp16 B [512][K] (n-major); id in [0, HEADS*64*K/8)
  int n = id & 63;
  int r = id >> 6;
  int kchunks = K >> 3;
  int kc = r % kchunks, h = r / kchunks;
  int k0 = kc * 8;
  half8 hi;
#pragma unroll
  for (int i = 0; i < 8; ++i)
    hi[i] = (_Float16)W[((size_t)h * K + k0 + i) * 64 + n];
  *(half8*)(Bc + (size_t)(h * 64 + n) * K + k0) = hi;
}

// ---------------------------------------------------------------------------
// Fused prep: block-range partitioned. Element counts per range:
//   build_nbr: 4096 rows / 4 waves-per-block          -> 1024 blocks [0,1024)
//   convA:     4096*256/4 = 262144 f4-elems / 256 thr -> 1024 blocks [1024,2048)
//   convW1:    8*64*(256/8) = 16384 / 256             ->   64 blocks [2048,2112)
//   convW2:    8*64*(512/8) = 32768 / 256             ->  128 blocks [2112,2240)
//   convW3:    same                                    ->  128 blocks [2240,2368)
// ---------------------------------------------------------------------------
__global__ __launch_bounds__(256) void prep_kernel(
    const float* __restrict__ adj, int* __restrict__ nbr_cnt,
    int* __restrict__ nbr, const float* __restrict__ features,
    _Float16* __restrict__ Ac1,
    const float* __restrict__ W1, const float* __restrict__ W2,
    const float* __restrict__ W3, _Float16* __restrict__ Bc1,
    _Float16* __restrict__ Bc2, _Float16* __restrict__ Bc3) {
  const int b = blockIdx.x;
  if (b < 1024) {
    int wave = b * 4 + (threadIdx.x >> 6);
    int lane = threadIdx.x & 63;
    const float4* arow = (const float4*)(adj + (size_t)wave * NODES);
    int* lst = nbr + (size_t)wave * MAXNBR;
    int base = 0;
    float4 a0 = arow[lane];
    float4 a1 = arow[64 + lane];
#pragma unroll 4
    for (int it = 0; it < 16; ++it) {
      float4 cur = a0;
      a0 = a1;
      if (it + 2 < 16) a1 = arow[(it + 2) * 64 + lane];
      const int colbase = it * 256 + lane * 4;
#pragma unroll
      for (int c = 0; c < 4; ++c) {
        float v = (c == 0) ? cur.x : (c == 1) ? cur.y : (c == 2) ? cur.z : cur.w;
        unsigned long long mask = __ballot(v > 0.0f);
        if (v > 0.0f) {
          int pos = base + __popcll(mask & ((1ull << lane) - 1ull));
          if (pos < MAXNBR) lst[pos] = colbase + c;
        }
        base += __popcll(mask);
      }
    }
    if (lane == 0) nbr_cnt[wave] = base < MAXNBR ? base : MAXNBR;
  } else if (b < 2048) {
    conv_a_elem(features, Ac1, 256, (b - 1024) * 256 + threadIdx.x);
  } else if (b < 2112) {
    conv_w_elem(W1, Bc1, 256, (b - 2048) * 256 + threadIdx.x);
  } else if (b < 2240) {
    conv_w_elem(W2, Bc2, 512, (b - 2112) * 256 + threadIdx.x);
  } else {
    conv_w_elem(W3, Bc3, 512, (b - 2240) * 256 + threadIdx.x);
  }
}

// ---------------------------------------------------------------------------
// C16[4096,512] = A[4096,Keff] * B[512,Keff]^T (fp16 in, fp32 accum, fp16 out)
// 64x64 tile, BK=32, 4 waves, 2x2 frags of 16x16x32 MFMA.
// Fused epilogue: s[h,m], d[h,m] computed fp32-exact from accumulators.
// ---------------------------------------------------------------------------
__global__ __launch_bounds__(256) void gemm_mfma(
    const _Float16* __restrict__ A,   // [4096][Keff]
    const _Float16* __restrict__ B,   // [512][Keff]  (n-major)
    _Float16* __restrict__ C16,       // [4096][512]
    const float* __restrict__ a_src,  // [8][64]
    const float* __restrict__ a_dst,  // [8][64]
    float* __restrict__ sbuf,         // [8][4096]
    float* __restrict__ dbuf,         // [8][4096]
    int Keff) {
  __shared__ _Float16 As[64 * 40];
  __shared__ _Float16 Bs[64 * 40];
  __shared__ float sS[2][64];
  __shared__ float sD[2][64];

  const int t    = threadIdx.x;
  const int m0   = blockIdx.y * 64;
  const int n0   = blockIdx.x * 64;
  const int h    = blockIdx.x;
  const int w    = t >> 6;
  const int lane = t & 63;
  const int wr   = (w >> 1) * 32;
  const int wc   = (w & 1) * 32;
  const int lr   = lane & 15;
  const int lk   = (lane >> 4) * 8;

  const int sr = t >> 2;
  const int sc = (t & 3) * 8;
  const _Float16* gA = A + (size_t)(m0 + sr) * Keff + sc;
  const _Float16* gB = B + (size_t)(n0 + sr) * Keff + sc;

  f32x4 acc00 = {}, acc01 = {}, acc10 = {}, acc11 = {};

  half8 av = *(const half8*)(gA);
  half8 bv = *(const half8*)(gB);

  for (int k0 = 0; k0 < Keff; k0 += 32) {
    __syncthreads();
    *(half8*)(&As[sr * 40 + sc]) = av;
    *(half8*)(&Bs[sr * 40 + sc]) = bv;
    __syncthreads();
    if (k0 + 32 < Keff) {
      av = *(const half8*)(gA + k0 + 32);
      bv = *(const half8*)(gB + k0 + 32);
    }
    half8 a0 = *(const half8*)(&As[(wr + lr) * 40 + lk]);
    half8 a1 = *(const half8*)(&As[(wr + 16 + lr) * 40 + lk]);
    half8 b0 = *(const half8*)(&Bs[(wc + lr) * 40 + lk]);
    half8 b1 = *(const half8*)(&Bs[(wc + 16 + lr) * 40 + lk]);
    acc00 = __builtin_amdgcn_mfma_f32_16x16x32_f16(a0, b0, acc00, 0, 0, 0);
    acc01 = __builtin_amdgcn_mfma_f32_16x16x32_f16(a0, b1, acc01, 0, 0, 0);
    acc10 = __builtin_amdgcn_mfma_f32_16x16x32_f16(a1, b0, acc10, 0, 0, 0);
    acc11 = __builtin_amdgcn_mfma_f32_16x16x32_f16(a1, b1, acc11, 0, 0, 0);
  }

  // C/D layout: col = lane&15, row = (lane>>4)*4 + reg  [m89/m91 verified]
  const int cm = (lane >> 4) * 4;
#pragma unroll
  for (int j = 0; j < 4; ++j) {
    int m  = m0 + wr + cm + j;
    int m2 = m + 16;
    C16[(size_t)m * FOUT + n0 + wc + lr]       = (_Float16)acc00[j];
    C16[(size_t)m * FOUT + n0 + wc + 16 + lr]  = (_Float16)acc01[j];
    C16[(size_t)m2 * FOUT + n0 + wc + lr]      = (_Float16)acc10[j];
    C16[(size_t)m2 * FOUT + n0 + wc + 16 + lr] = (_Float16)acc11[j];
  }

  // fused s/d epilogue (fp32-exact from accumulators)
  const float as0 = a_src[(h << 6) + wc + lr];
  const float as1 = a_src[(h << 6) + wc + 16 + lr];
  const float ad0 = a_dst[(h << 6) + wc + lr];
  const float ad1 = a_dst[(h << 6) + wc + 16 + lr];
  float ps[8], pd[8];
#pragma unroll
  for (int j = 0; j < 4; ++j) {
    ps[j]     = acc00[j] * as0 + acc01[j] * as1;
    ps[4 + j] = acc10[j] * as0 + acc11[j] * as1;
    pd[j]     = acc00[j] * ad0 + acc01[j] * ad1;
    pd[4 + j] = acc10[j] * ad0 + acc11[j] * ad1;
  }
#pragma unroll
  for (int off = 1; off < 16; off <<= 1) {
#pragma unroll
    for (int j = 0; j < 8; ++j) {
      ps[j] += __shfl_xor(ps[j], off);
      pd[j] += __shfl_xor(pd[j], off);
    }
  }
  if (lr == 0) {
#pragma unroll
    for (int j = 0; j < 4; ++j) {
      sS[w & 1][wr + cm + j]      = ps[j];
      sS[w & 1][wr + 16 + cm + j] = ps[4 + j];
      sD[w & 1][wr + cm + j]      = pd[j];
      sD[w & 1][wr + 16 + cm + j] = pd[4 + j];
    }
  }
  __syncthreads();
  if (t < 64) {
    sbuf[(size_t)h * NODES + m0 + t] = sS[0][t] + sS[1][t];
    dbuf[(size_t)h * NODES + m0 + t] = sD[0][t] + sD[1][t];
  }
}

// ---------------------------------------------------------------------------
// Sparse masked softmax + PV + ELU. fp16 Wh16 gather, 16-slot windows,
// 1-deep software prefetch (R12-proven structure) + setprio around gather.
// WRITE_AC=1: write next layer's A as fp16 [4096][512]. =0: fp32 out.
// ---------------------------------------------------------------------------
template <int WRITE_AC>
__global__ __launch_bounds__(512) void attn_kernel(
    const int* __restrict__ nbr_cnt, const int* __restrict__ nbr,
    const float* __restrict__ s, const float* __restrict__ d,
    const _Float16* __restrict__ Wh16,
    float* __restrict__ out, _Float16* __restrict__ Ac) {
  __shared__ int   lst_lds[MAXNBR];
  __shared__ float w_lds[HEADS][MAXNBR];

  const int i    = blockIdx.x;
  const int tid  = threadIdx.x;
  const int h    = tid >> 6;
  const int lane = tid & 63;
  const int cnt  = nbr_cnt[i];

  if (tid < MAXNBR)
    lst_lds[tid] = (tid < cnt) ? nbr[(size_t)i * MAXNBR + tid] : i;
  __syncthreads();

  const float s_i = s[(size_t)h * NODES + i];
  const float* dh = d + (size_t)h * NODES;
  float e0 = -1e30f, e1 = -1e30f;
  if (lane < cnt) {
    float e = s_i + dh[lst_lds[lane]];
    e0 = (e >= 0.0f) ? e : 0.2f * e;
  }
  if (lane + 64 < cnt) {
    float e = s_i + dh[lst_lds[lane + 64]];
    e1 = (e >= 0.0f) ? e : 0.2f * e;
  }
  float m = fmaxf(e0, e1);
#pragma unroll
  for (int off = 32; off; off >>= 1) m = fmaxf(m, __shfl_xor(m, off));
  float w0 = (lane < cnt) ? __expf(e0 - m) : 0.0f;
  float w1 = (lane + 64 < cnt) ? __expf(e1 - m) : 0.0f;
  w_lds[h][lane]      = w0;
  w_lds[h][lane + 64] = w1;
  float den = w0 + w1;
#pragma unroll
  for (int off = 32; off; off >>= 1) den += __shfl_xor(den, off);
  const float rden = 1.0f / den;
  __syncthreads();

  // gather: 8 subgroups of 8 lanes; lane covers 8 dims via half8; 2 chains,
  // 16 nbrs/iter, next-iter rows prefetched during current FMAs (R12 exact).
  const int g  = lane >> 3;
  const int d8 = (lane & 7) * 8;
  const int cnt16 = (cnt + 15) & ~15;
  const _Float16* base = Wh16 + h * HID + d8;
  float aA[8] = {}, aB[8] = {};

  __builtin_amdgcn_s_setprio(1);
  int ja = lst_lds[g], jb = lst_lds[g + 8];
  float wa = w_lds[h][g], wb = w_lds[h][g + 8];
  half8 va = *(const half8*)(base + (size_t)ja * FOUT);
  half8 vb = *(const half8*)(base + (size_t)jb * FOUT);

  for (int t0 = 16; t0 < cnt16; t0 += 16) {
    const int ta2 = t0 + g, tb2 = ta2 + 8;
    const int ja2 = lst_lds[ta2], jb2 = lst_lds[tb2];
    const float wa2 = w_lds[h][ta2], wb2 = w_lds[h][tb2];
    const half8 va2 = *(const half8*)(base + (size_t)ja2 * FOUT);
    const half8 vb2 = *(const half8*)(base + (size_t)jb2 * FOUT);
#pragma unroll
    for (int q = 0; q < 8; ++q) {
      aA[q] += wa * (float)va[q];
      aB[q] += wb * (float)vb[q];
    }
    wa = wa2; wb = wb2; va = va2; vb = vb2;
  }
#pragma unroll
  for (int q = 0; q < 8; ++q) {
    aA[q] += wa * (float)va[q];
    aB[q] += wb * (float)vb[q];
  }
  __builtin_amdgcn_s_setprio(0);

  float acc[8];
#pragma unroll
  for (int q = 0; q < 8; ++q) acc[q] = aA[q] + aB[q];
#pragma unroll
  for (int off = 8; off <= 32; off <<= 1)
#pragma unroll
    for (int q = 0; q < 8; ++q) acc[q] += __shfl_xor(acc[q], off);

  if (lane < 8) {
    float o[8];
#pragma unroll
    for (int q = 0; q < 8; ++q) {
      float v = acc[q] * rden;
      o[q] = (v > 0.0f) ? v : (__expf(v) - 1.0f);
    }
    if (WRITE_AC) {
      half8 hi;
#pragma unroll
      for (int q = 0; q < 8; ++q) hi[q] = (_Float16)o[q];
      *(half8*)(Ac + (size_t)i * FOUT + h * HID + d8) = hi;
    } else {
      float* ob = out + (size_t)i * FOUT + h * HID + d8;
      *(float4*)(ob)     = make_float4(o[0], o[1], o[2], o[3]);
      *(float4*)(ob + 4) = make_float4(o[4], o[5], o[6], o[7]);
    }
  }
}

// ---------------------------------------------------------------------------
extern "C" void kernel_launch(void* const* d_in, const int* in_sizes, int n_in,
                              void* d_out, int out_size, void* d_ws,
                              size_t ws_size, hipStream_t stream) {
  const float* features = (const float*)d_in[0];
  const float* adj      = (const float*)d_in[1];
  const float* W1  = (const float*)d_in[2];
  const float* a1s = (const float*)d_in[3];
  const float* a1d = (const float*)d_in[4];
  const float* W2  = (const float*)d_in[5];
  const float* a2s = (const float*)d_in[6];
  const float* a2d = (const float*)d_in[7];
  const float* W3  = (const float*)d_in[8];
  const float* a3s = (const float*)d_in[9];
  const float* a3d = (const float*)d_in[10];
  float* out = (float*)d_out;

  char* ws = (char*)d_ws;
  size_t off = 0;
  int* nbr_cnt = (int*)(ws + off); off += (size_t)NODES * 4;
  int* nbr     = (int*)(ws + off); off += (size_t)NODES * MAXNBR * 4;
  _Float16* Wh16 = (_Float16*)(ws + off); off += (size_t)NODES * FOUT * 2;
  float* sbuf  = (float*)(ws + off); off += (size_t)HEADS * NODES * 4;
  float* dbuf  = (float*)(ws + off); off += (size_t)HEADS * NODES * 4;
  _Float16* Ac1 = (_Float16*)(ws + off); off += (size_t)NODES * 256 * 2;   // layer-1 A (fp16)
  _Float16* Ac2 = (_Float16*)(ws + off); off += (size_t)NODES * FOUT * 2;  // layers 2/3 A
  _Float16* Bc1 = (_Float16*)(ws + off); off += (size_t)FOUT * 256 * 2;
  _Float16* Bc2 = (_Float16*)(ws + off); off += (size_t)FOUT * 512 * 2;
  _Float16* Bc3 = (_Float16*)(ws + off); off += (size_t)FOUT * 512 * 2;

  prep_kernel<<<2368, 256, 0, stream>>>(adj, nbr_cnt, nbr, features, Ac1,
                                        W1, W2, W3, Bc1, Bc2, Bc3);

  dim3 gg(HEADS, NODES / 64);

  // ---- layer 1 (Keff=256, plain fp16) ----
  gemm_mfma<<<gg, 256, 0, stream>>>(Ac1, Bc1, Wh16, a1s, a1d, sbuf, dbuf, 256);
  attn_kernel<1><<<NODES, 512, 0, stream>>>(nbr_cnt, nbr, sbuf, dbuf, Wh16, out, Ac2);
  // ---- layer 2 (Keff=512, plain fp16) ----
  gemm_mfma<<<gg, 256, 0, stream>>>(Ac2, Bc2, Wh16, a2s, a2d, sbuf, dbuf, 512);
  attn_kernel<1><<<NODES, 512, 0, stream>>>(nbr_cnt, nbr, sbuf, dbuf, Wh16, out, Ac2);
  // ---- layer 3 (Keff=512, plain fp16) ----
  gemm_mfma<<<gg, 256, 0, stream>>>(Ac2, Bc3, Wh16, a3s, a3d, sbuf, dbuf, 512);
  attn_kernel<0><<<NODES, 512, 0, stream>>>(nbr_cnt, nbr, sbuf, dbuf, Wh16, out, Ac2);
}

// Round 17
// 114.261 us; speedup vs baseline: 1.1176x; 1.0320x over previous
//
#include <hip/hip_runtime.h>
#include <hip/hip_bf16.h>
#include <math.h>

// GAT, 3 layers, N=4096, H=8, O=64, F_in=256 then 512.
// Sparse softmax over ~1%-dense adj (+self loops) is EXACT vs masked dense.
//
// R2-R12: MFMA GEMMs (plain fp16); fused prep/sd; fp16 Wh gather with
//   16-slot windows + 1-deep prefetch (115.9us best).
// R13-R15: deeper pipelines & setprio all neutral/regressions -> reverted.
// R16(this): build_nbr split 2 waves/row — each wave loads its 2048-col half
//   as 8 straight-line float4s (all in flight before the ALU chain), ballot
//   chain is 32 steps (was 64), emit via LDS with cross-half offset.
//   Same neighbor order (half0 = chunks 0-7, half1 = chunks 8-15).

#define NODES 4096
#define HEADS 8
#define HID   64
#define FOUT  512   // HEADS*HID
#define MAXNBR 128

typedef _Float16 half8 __attribute__((ext_vector_type(8)));
typedef _Float16 half4 __attribute__((ext_vector_type(4)));
typedef float f32x4 __attribute__((ext_vector_type(4)));

// ---------------------------------------------------------------------------
// device helpers for the fused prep kernel
// ---------------------------------------------------------------------------
__device__ inline void conv_a_elem(const float* __restrict__ in,
                                   _Float16* __restrict__ out, int K, int id) {
  // plain fp16 A [4096][K]; id in [0, NODES*K/4)
  int perRow = K >> 2;
  int m = id / perRow, c = (id - m * perRow) * 4;
  float4 v = *(const float4*)(in + (size_t)m * K + c);
  half4 hi;
  hi[0] = (_Float16)v.x; hi[1] = (_Float16)v.y;
  hi[2] = (_Float16)v.z; hi[3] = (_Float16)v.w;
  *(half4*)(out + (size_t)m * K + c) = hi;
}

__device__ inline void conv_w_elem(const float* __restrict__ W,
                                   _Float16* __restrict__ Bc, int K, int id) {
  // plain fp16 B [512][K] (n-major); id in [0, HEADS*64*K/8)
  int n = id & 63;
  int r = id >> 6;
  int kchunks = K >> 3;
  int kc = r % kchunks, h = r / kchunks;
  int k0 = kc * 8;
  half8 hi;
#pragma unroll
  for (int i = 0; i < 8; ++i)
    hi[i] = (_Float16)W[((size_t)h * K + k0 + i) * 64 + n];
  *(half8*)(Bc + (size_t)(h * 64 + n) * K + k0) = hi;
}

// ---------------------------------------------------------------------------
// Fused prep: block-range partitioned. Element counts per range (re-derived):
//   build_nbr: 4096 rows x 2 waves/row / 4 waves/blk  -> 2048 blocks [0,2048)
//   convA:     4096*256/4 = 262144 f4-elems / 256 thr -> 1024 blocks [2048,3072)
//   convW1:    8*64*(256/8) = 16384 / 256             ->   64 blocks [3072,3136)
//   convW2:    8*64*(512/8) = 32768 / 256             ->  128 blocks [3136,3264)
//   convW3:    same                                    ->  128 blocks [3264,3392)
// ---------------------------------------------------------------------------
__global__ __launch_bounds__(256) void prep_kernel(
    const float* __restrict__ adj, int* __restrict__ nbr_cnt,
    int* __restrict__ nbr, const float* __restrict__ features,
    _Float16* __restrict__ Ac1,
    const float* __restrict__ W1, const float* __restrict__ W2,
    const float* __restrict__ W3, _Float16* __restrict__ Bc1,
    _Float16* __restrict__ Bc2, _Float16* __restrict__ Bc3) {
  __shared__ int tmp[2][2][MAXNBR];   // [row-in-block][half][slot]
  __shared__ int halfcnt[2][2];

  const int b = blockIdx.x;
  if (b < 2048) {
    // ---- build_nbr: 2 waves per row, half-row each ----
    const int wid  = threadIdx.x >> 6;   // 0..3
    const int lane = threadIdx.x & 63;
    const int r    = wid >> 1;           // row in block (0,1)
    const int half = wid & 1;            // which half of the row
    const int row  = b * 2 + r;
    const float4* arow =
        (const float4*)(adj + (size_t)row * NODES + half * 2048);

    // load the whole half-row into registers: 8 straight-line float4 loads
    float4 v0 = arow[lane];
    float4 v1 = arow[64 + lane];
    float4 v2 = arow[128 + lane];
    float4 v3 = arow[192 + lane];
    float4 v4 = arow[256 + lane];
    float4 v5 = arow[320 + lane];
    float4 v6 = arow[384 + lane];
    float4 v7 = arow[448 + lane];

    int base = 0;
    int* buf = &tmp[r][half][0];
    const int colhalf = half * 2048;
#pragma unroll
    for (int it = 0; it < 8; ++it) {
      float4 cur = (it == 0) ? v0 : (it == 1) ? v1 : (it == 2) ? v2 :
                   (it == 3) ? v3 : (it == 4) ? v4 : (it == 5) ? v5 :
                   (it == 6) ? v6 : v7;
      const int colbase = colhalf + it * 256 + lane * 4;
#pragma unroll
      for (int c = 0; c < 4; ++c) {
        float v = (c == 0) ? cur.x : (c == 1) ? cur.y : (c == 2) ? cur.z
                                                                 : cur.w;
        unsigned long long mask = __ballot(v > 0.0f);
        if (v > 0.0f) {
          int pos = base + __popcll(mask & ((1ull << lane) - 1ull));
          if (pos < MAXNBR) buf[pos] = colbase + c;
        }
        base += __popcll(mask);
      }
    }
    if (lane == 0) halfcnt[r][half] = base;
    __syncthreads();

    const int cnt0 = halfcnt[r][0];
    const int cnt1 = halfcnt[r][1];
    int* lst = nbr + (size_t)row * MAXNBR;
    if (half == 0) {
      const int lim = cnt0 < MAXNBR ? cnt0 : MAXNBR;
      for (int t = lane; t < lim; t += 64) lst[t] = tmp[r][0][t];
      // pad the tail with self-loops (weight will be 0 in attn)
      const int tot = cnt0 + cnt1;
      const int cap = tot < MAXNBR ? tot : MAXNBR;
      for (int t = cap + lane; t < MAXNBR; t += 64) lst[t] = row;
      if (lane == 0) nbr_cnt[row] = cap;
    } else {
      int lim = cnt1;
      if (cnt0 + lim > MAXNBR) lim = MAXNBR - cnt0;
      for (int t = lane; t < lim; t += 64) lst[cnt0 + t] = tmp[r][1][t];
    }
  } else if (b < 3072) {
    conv_a_elem(features, Ac1, 256, (b - 2048) * 256 + threadIdx.x);
  } else if (b < 3136) {
    conv_w_elem(W1, Bc1, 256, (b - 3072) * 256 + threadIdx.x);
  } else if (b < 3264) {
    conv_w_elem(W2, Bc2, 512, (b - 3136) * 256 + threadIdx.x);
  } else {
    conv_w_elem(W3, Bc3, 512, (b - 3264) * 256 + threadIdx.x);
  }
}

// ---------------------------------------------------------------------------
// C16[4096,512] = A[4096,Keff] * B[512,Keff]^T (fp16 in, fp32 accum, fp16 out)
// 64x64 tile, BK=32, 4 waves, 2x2 frags of 16x16x32 MFMA.
// Fused epilogue: s[h,m], d[h,m] computed fp32-exact from accumulators.
// ---------------------------------------------------------------------------
__global__ __launch_bounds__(256) void gemm_mfma(
    const _Float16* __restrict__ A,   // [4096][Keff]
    const _Float16* __restrict__ B,   // [512][Keff]  (n-major)
    _Float16* __restrict__ C16,       // [4096][512]
    const float* __restrict__ a_src,  // [8][64]
    const float* __restrict__ a_dst,  // [8][64]
    float* __restrict__ sbuf,         // [8][4096]
    float* __restrict__ dbuf,         // [8][4096]
    int Keff) {
  __shared__ _Float16 As[64 * 40];
  __shared__ _Float16 Bs[64 * 40];
  __shared__ float sS[2][64];
  __shared__ float sD[2][64];

  const int t    = threadIdx.x;
  const int m0   = blockIdx.y * 64;
  const int n0   = blockIdx.x * 64;
  const int h    = blockIdx.x;
  const int w    = t >> 6;
  const int lane = t & 63;
  const int wr   = (w >> 1) * 32;
  const int wc   = (w & 1) * 32;
  const int lr   = lane & 15;
  const int lk   = (lane >> 4) * 8;

  const int sr = t >> 2;
  const int sc = (t & 3) * 8;
  const _Float16* gA = A + (size_t)(m0 + sr) * Keff + sc;
  const _Float16* gB = B + (size_t)(n0 + sr) * Keff + sc;

  f32x4 acc00 = {}, acc01 = {}, acc10 = {}, acc11 = {};

  half8 av = *(const half8*)(gA);
  half8 bv = *(const half8*)(gB);

  for (int k0 = 0; k0 < Keff; k0 += 32) {
    __syncthreads();
    *(half8*)(&As[sr * 40 + sc]) = av;
    *(half8*)(&Bs[sr * 40 + sc]) = bv;
    __syncthreads();
    if (k0 + 32 < Keff) {
      av = *(const half8*)(gA + k0 + 32);
      bv = *(const half8*)(gB + k0 + 32);
    }
    half8 a0 = *(const half8*)(&As[(wr + lr) * 40 + lk]);
    half8 a1 = *(const half8*)(&As[(wr + 16 + lr) * 40 + lk]);
    half8 b0 = *(const half8*)(&Bs[(wc + lr) * 40 + lk]);
    half8 b1 = *(const half8*)(&Bs[(wc + 16 + lr) * 40 + lk]);
    acc00 = __builtin_amdgcn_mfma_f32_16x16x32_f16(a0, b0, acc00, 0, 0, 0);
    acc01 = __builtin_amdgcn_mfma_f32_16x16x32_f16(a0, b1, acc01, 0, 0, 0);
    acc10 = __builtin_amdgcn_mfma_f32_16x16x32_f16(a1, b0, acc10, 0, 0, 0);
    acc11 = __builtin_amdgcn_mfma_f32_16x16x32_f16(a1, b1, acc11, 0, 0, 0);
  }

  // C/D layout: col = lane&15, row = (lane>>4)*4 + reg  [m89/m91 verified]
  const int cm = (lane >> 4) * 4;
#pragma unroll
  for (int j = 0; j < 4; ++j) {
    int m  = m0 + wr + cm + j;
    int m2 = m + 16;
    C16[(size_t)m * FOUT + n0 + wc + lr]       = (_Float16)acc00[j];
    C16[(size_t)m * FOUT + n0 + wc + 16 + lr]  = (_Float16)acc01[j];
    C16[(size_t)m2 * FOUT + n0 + wc + lr]      = (_Float16)acc10[j];
    C16[(size_t)m2 * FOUT + n0 + wc + 16 + lr] = (_Float16)acc11[j];
  }

  // fused s/d epilogue (fp32-exact from accumulators)
  const float as0 = a_src[(h << 6) + wc + lr];
  const float as1 = a_src[(h << 6) + wc + 16 + lr];
  const float ad0 = a_dst[(h << 6) + wc + lr];
  const float ad1 = a_dst[(h << 6) + wc + 16 + lr];
  float ps[8], pd[8];
#pragma unroll
  for (int j = 0; j < 4; ++j) {
    ps[j]     = acc00[j] * as0 + acc01[j] * as1;
    ps[4 + j] = acc10[j] * as0 + acc11[j] * as1;
    pd[j]     = acc00[j] * ad0 + acc01[j] * ad1;
    pd[4 + j] = acc10[j] * ad0 + acc11[j] * ad1;
  }
#pragma unroll
  for (int off = 1; off < 16; off <<= 1) {
#pragma unroll
    for (int j = 0; j < 8; ++j) {
      ps[j] += __shfl_xor(ps[j], off);
      pd[j] += __shfl_xor(pd[j], off);
    }
  }
  if (lr == 0) {
#pragma unroll
    for (int j = 0; j < 4; ++j) {
      sS[w & 1][wr + cm + j]      = ps[j];
      sS[w & 1][wr + 16 + cm + j] = ps[4 + j];
      sD[w & 1][wr + cm + j]      = pd[j];
      sD[w & 1][wr + 16 + cm + j] = pd[4 + j];
    }
  }
  __syncthreads();
  if (t < 64) {
    sbuf[(size_t)h * NODES + m0 + t] = sS[0][t] + sS[1][t];
    dbuf[(size_t)h * NODES + m0 + t] = sD[0][t] + sD[1][t];
  }
}

// ---------------------------------------------------------------------------
// Sparse masked softmax + PV + ELU. fp16 Wh16 gather, 16-slot windows,
// 1-deep software prefetch (R12-proven structure, setprio removed).
// WRITE_AC=1: write next layer's A as fp16 [4096][512]. =0: fp32 out.
// ---------------------------------------------------------------------------
template <int WRITE_AC>
__global__ __launch_bounds__(512) void attn_kernel(
    const int* __restrict__ nbr_cnt, const int* __restrict__ nbr,
    const float* __restrict__ s, const float* __restrict__ d,
    const _Float16* __restrict__ Wh16,
    float* __restrict__ out, _Float16* __restrict__ Ac) {
  __shared__ int   lst_lds[MAXNBR];
  __shared__ float w_lds[HEADS][MAXNBR];

  const int i    = blockIdx.x;
  const int tid  = threadIdx.x;
  const int h    = tid >> 6;
  const int lane = tid & 63;
  const int cnt  = nbr_cnt[i];

  if (tid < MAXNBR)
    lst_lds[tid] = (tid < cnt) ? nbr[(size_t)i * MAXNBR + tid] : i;
  __syncthreads();

  const float s_i = s[(size_t)h * NODES + i];
  const float* dh = d + (size_t)h * NODES;
  float e0 = -1e30f, e1 = -1e30f;
  if (lane < cnt) {
    float e = s_i + dh[lst_lds[lane]];
    e0 = (e >= 0.0f) ? e : 0.2f * e;
  }
  if (lane + 64 < cnt) {
    float e = s_i + dh[lst_lds[lane + 64]];
    e1 = (e >= 0.0f) ? e : 0.2f * e;
  }
  float m = fmaxf(e0, e1);
#pragma unroll
  for (int off = 32; off; off >>= 1) m = fmaxf(m, __shfl_xor(m, off));
  float w0 = (lane < cnt) ? __expf(e0 - m) : 0.0f;
  float w1 = (lane + 64 < cnt) ? __expf(e1 - m) : 0.0f;
  w_lds[h][lane]      = w0;
  w_lds[h][lane + 64] = w1;
  float den = w0 + w1;
#pragma unroll
  for (int off = 32; off; off >>= 1) den += __shfl_xor(den, off);
  const float rden = 1.0f / den;
  __syncthreads();

  // gather: 8 subgroups of 8 lanes; lane covers 8 dims via half8; 2 chains,
  // 16 nbrs/iter, next-iter rows prefetched during current FMAs (R12 exact).
  const int g  = lane >> 3;
  const int d8 = (lane & 7) * 8;
  const int cnt16 = (cnt + 15) & ~15;
  const _Float16* base = Wh16 + h * HID + d8;
  float aA[8] = {}, aB[8] = {};

  int ja = lst_lds[g], jb = lst_lds[g + 8];
  float wa = w_lds[h][g], wb = w_lds[h][g + 8];
  half8 va = *(const half8*)(base + (size_t)ja * FOUT);
  half8 vb = *(const half8*)(base + (size_t)jb * FOUT);

  for (int t0 = 16; t0 < cnt16; t0 += 16) {
    const int ta2 = t0 + g, tb2 = ta2 + 8;
    const int ja2 = lst_lds[ta2], jb2 = lst_lds[tb2];
    const float wa2 = w_lds[h][ta2], wb2 = w_lds[h][tb2];
    const half8 va2 = *(const half8*)(base + (size_t)ja2 * FOUT);
    const half8 vb2 = *(const half8*)(base + (size_t)jb2 * FOUT);
#pragma unroll
    for (int q = 0; q < 8; ++q) {
      aA[q] += wa * (float)va[q];
      aB[q] += wb * (float)vb[q];
    }
    wa = wa2; wb = wb2; va = va2; vb = vb2;
  }
#pragma unroll
  for (int q = 0; q < 8; ++q) {
    aA[q] += wa * (float)va[q];
    aB[q] += wb * (float)vb[q];
  }

  float acc[8];
#pragma unroll
  for (int q = 0; q < 8; ++q) acc[q] = aA[q] + aB[q];
#pragma unroll
  for (int off = 8; off <= 32; off <<= 1)
#pragma unroll
    for (int q = 0; q < 8; ++q) acc[q] += __shfl_xor(acc[q], off);

  if (lane < 8) {
    float o[8];
#pragma unroll
    for (int q = 0; q < 8; ++q) {
      float v = acc[q] * rden;
      o[q] = (v > 0.0f) ? v : (__expf(v) - 1.0f);
    }
    if (WRITE_AC) {
      half8 hi;
#pragma unroll
      for (int q = 0; q < 8; ++q) hi[q] = (_Float16)o[q];
      *(half8*)(Ac + (size_t)i * FOUT + h * HID + d8) = hi;
    } else {
      float* ob = out + (size_t)i * FOUT + h * HID + d8;
      *(float4*)(ob)     = make_float4(o[0], o[1], o[2], o[3]);
      *(float4*)(ob + 4) = make_float4(o[4], o[5], o[6], o[7]);
    }
  }
}

// ---------------------------------------------------------------------------
extern "C" void kernel_launch(void* const* d_in, const int* in_sizes, int n_in,
                              void* d_out, int out_size, void* d_ws,
                              size_t ws_size, hipStream_t stream) {
  const float* features = (const float*)d_in[0];
  const float* adj      = (const float*)d_in[1];
  const float* W1  = (const float*)d_in[2];
  const float* a1s = (const float*)d_in[3];
  const float* a1d = (const float*)d_in[4];
  const float* W2  = (const float*)d_in[5];
  const float* a2s = (const float*)d_in[6];
  const float* a2d = (const float*)d_in[7];
  const float* W3  = (const float*)d_in[8];
  const float* a3s = (const float*)d_in[9];
  const float* a3d = (const float*)d_in[10];
  float* out = (float*)d_out;

  char* ws = (char*)d_ws;
  size_t off = 0;
  int* nbr_cnt = (int*)(ws + off); off += (size_t)NODES * 4;
  int* nbr     = (int*)(ws + off); off += (size_t)NODES * MAXNBR * 4;
  _Float16* Wh16 = (_Float16*)(ws + off); off += (size_t)NODES * FOUT * 2;
  float* sbuf  = (float*)(ws + off); off += (size_t)HEADS * NODES * 4;
  float* dbuf  = (float*)(ws + off); off += (size_t)HEADS * NODES * 4;
  _Float16* Ac1 = (_Float16*)(ws + off); off += (size_t)NODES * 256 * 2;   // layer-1 A (fp16)
  _Float16* Ac2 = (_Float16*)(ws + off); off += (size_t)NODES * FOUT * 2;  // layers 2/3 A
  _Float16* Bc1 = (_Float16*)(ws + off); off += (size_t)FOUT * 256 * 2;
  _Float16* Bc2 = (_Float16*)(ws + off); off += (size_t)FOUT * 512 * 2;
  _Float16* Bc3 = (_Float16*)(ws + off); off += (size_t)FOUT * 512 * 2;

  prep_kernel<<<3392, 256, 0, stream>>>(adj, nbr_cnt, nbr, features, Ac1,
                                        W1, W2, W3, Bc1, Bc2, Bc3);

  dim3 gg(HEADS, NODES / 64);

  // ---- layer 1 (Keff=256, plain fp16) ----
  gemm_mfma<<<gg, 256, 0, stream>>>(Ac1, Bc1, Wh16, a1s, a1d, sbuf, dbuf, 256);
  attn_kernel<1><<<NODES, 512, 0, stream>>>(nbr_cnt, nbr, sbuf, dbuf, Wh16, out, Ac2);
  // ---- layer 2 (Keff=512, plain fp16) ----
  gemm_mfma<<<gg, 256, 0, stream>>>(Ac2, Bc2, Wh16, a2s, a2d, sbuf, dbuf, 512);
  attn_kernel<1><<<NODES, 512, 0, stream>>>(nbr_cnt, nbr, sbuf, dbuf, Wh16, out, Ac2);
  // ---- layer 3 (Keff=512, plain fp16) ----
  gemm_mfma<<<gg, 256, 0, stream>>>(Ac2, Bc3, Wh16, a3s, a3d, sbuf, dbuf, 512);
  attn_kernel<0><<<NODES, 512, 0, stream>>>(nbr_cnt, nbr, sbuf, dbuf, Wh16, out, Ac2);
}